// Round 6
// baseline (745.512 us; speedup 1.0000x reference)
//
#include <hip/hip_runtime.h>
#include <hip/hip_bf16.h>
#include <math.h>

// Problem constants
#define TOKENS   16384        // T*Z
#define DDIM     1024
#define NEXP     64
#define PSLOT    32
#define NSLOTS   2048         // NEXP*PSLOT
#define HDIM     1024
#define LN_EPS   1e-5f
#define KSPLIT   8            // split-K factor for GEMM2 (D^T x)

typedef __bf16 b16x8 __attribute__((ext_vector_type(8)));
typedef float  f32x4 __attribute__((ext_vector_type(4)));

__device__ __forceinline__ unsigned short f2b(float f) {
    union { float f; unsigned u; } v; v.f = f;
    unsigned r = v.u + 0x7FFF + ((v.u >> 16) & 1);   // RNE
    return (unsigned short)(r >> 16);
}
__device__ __forceinline__ float b2f(unsigned short u) {
    union { unsigned u; float f; } v; v.u = ((unsigned)u) << 16; return v.f;
}

__device__ __forceinline__ void load_lds16(const void* g, void* l) {
    __builtin_amdgcn_global_load_lds(
        (const __attribute__((address_space(1))) void*)g,
        (__attribute__((address_space(3))) void*)l, 16, 0, 0);
}
__device__ __forceinline__ void load_lds4(const void* g, void* l) {
    __builtin_amdgcn_global_load_lds(
        (const __attribute__((address_space(1))) void*)g,
        (__attribute__((address_space(3))) void*)l, 4, 0, 0);
}

// ---------------------------------------------------------------------------
// 256x256 8-phase pipelined bf16 MFMA GEMM, NT layout:
//   C[M,N] = A[M,K] * B[N,K]^T (+ bias over N), split-K via gridDim.z.
// OT = float (f32 out) or unsigned short (bf16 out, halves epilogue traffic).
// 512 threads = 8 waves (2 M x 4 N), per-wave output 128x64.
// BK=64; LDS = 2 bufs x (A 256x64 + B 256x64) bf16 = 128KB.
// Counted vmcnt(6) at phases 4/8 only; final iteration peeled. XCD-aware
// block swizzle (A-panel L2 reuse). XOR k-slot LDS swizzle (conflict-free).
// ---------------------------------------------------------------------------
template<bool BIAS, typename OT>
__global__ __launch_bounds__(512, 2) void gemm_nt_256(
    const unsigned short* __restrict__ A,   // [M, K] bf16
    const unsigned short* __restrict__ B,   // [N, K] bf16
    const float* __restrict__ bias,          // [N] or null
    OT* __restrict__ C,                      // [gridDim.z][M, N]
    int M, int N, int K)
{
    __shared__ unsigned short lds[2][2][256 * 64];   // [buf][A/B][r'*64+col]
    const int tid  = threadIdx.x;
    const int wave = tid >> 6;
    const int lane = tid & 63;
    const int wr = wave >> 2;        // 0..1
    const int wc = wave & 3;         // 0..3
    const int fr = lane & 15;
    const int fs = lane >> 4;        // 0..3
    const int kswz = ((lane & 7) ^ (lane >> 3)) * 8;  // pre-swizzled global k

    // XCD-aware swizzle: contiguous chunk of output tiles per XCD (T1, m204)
    const int gx  = (int)gridDim.x, gy = (int)gridDim.y;
    const int nwg = gx * gy;
    const int wg  = (int)blockIdx.y * gx + (int)blockIdx.x;
    const int swz = (wg & 7) * (nwg >> 3) + (wg >> 3);
    const int m0 = (swz / gx) * 256;
    const int n0 = (swz % gx) * 256;

    const int kc = K / gridDim.z;
    const int kb = blockIdx.z * kc;
    C += (size_t)blockIdx.z * M * N;
    const int NT = kc >> 6;          // K-tiles (>=16 for all our shapes)

    f32x4 acc[8][4] = {};
    b16x8 Ag[4][2], Bf[2][2], Bs2[2][2];

#define KOF(T)   (kb + (T) * 64)

#define STAGE_A(BUF, T, R0) { \
    const int k0_ = KOF(T); \
    _Pragma("unroll") for (int hh = 0; hh < 2; ++hh) { \
        const int rp_ = (R0) + hh * 64 + wave * 8 + (lane >> 3); \
        const int L_  = ((rp_ >> 6) & 1) * 128 + ((rp_ >> 7) & 1) * 64 + (rp_ & 63); \
        load_lds16(A + (size_t)(m0 + L_) * K + k0_ + kswz, \
                   &lds[BUF][0][((R0) + hh * 64 + wave * 8) * 64]); } }

#define STAGE_B(BUF, T, R0) { \
    const int k0_ = KOF(T); \
    _Pragma("unroll") for (int hh = 0; hh < 2; ++hh) { \
        const int rp_ = (R0) + hh * 64 + wave * 8 + (lane >> 3); \
        const int L_  = ((rp_ >> 5) & 3) * 64 + ((rp_ >> 7) & 1) * 32 + (rp_ & 31); \
        load_lds16(B + (size_t)(n0 + L_) * K + k0_ + kswz, \
                   &lds[BUF][1][((R0) + hh * 64 + wave * 8) * 64]); } }

#define LDA_G(BUF, IBASE) \
    _Pragma("unroll") for (int ii = 0; ii < 4; ++ii) { \
        const int rp_ = (IBASE) + 64 * wr + ii * 16 + fr; \
        _Pragma("unroll") for (int h = 0; h < 2; ++h) \
            Ag[ii][h] = *(const b16x8*)&lds[BUF][0][rp_ * 64 + (((h * 4 + fs) ^ (rp_ & 7)) * 8)]; }

#define LDB_G(BUF, JBASE, DST) \
    _Pragma("unroll") for (int jj = 0; jj < 2; ++jj) { \
        const int rp_ = (JBASE) + 32 * wc + jj * 16 + fr; \
        _Pragma("unroll") for (int h = 0; h < 2; ++h) \
            DST[jj][h] = *(const b16x8*)&lds[BUF][1][rp_ * 64 + (((h * 4 + fs) ^ (rp_ & 7)) * 8)]; }

#define MFMA_Q(IB, JB, BREG) \
    __builtin_amdgcn_s_setprio(1); \
    _Pragma("unroll") for (int ii = 0; ii < 4; ++ii) \
    _Pragma("unroll") for (int jj = 0; jj < 2; ++jj) \
    _Pragma("unroll") for (int h = 0; h < 2; ++h) \
        acc[(IB) + ii][(JB) + jj] = __builtin_amdgcn_mfma_f32_16x16x32_bf16( \
            Ag[ii][h], BREG[jj][h], acc[(IB) + ii][(JB) + jj], 0, 0, 0); \
    __builtin_amdgcn_s_setprio(0);

#define BAR1  { __builtin_amdgcn_s_barrier(); __builtin_amdgcn_sched_barrier(0); }
#define BAR2  { __builtin_amdgcn_s_barrier(); }
#define VMW6  { asm volatile("s_waitcnt vmcnt(6)" ::: "memory"); \
                __builtin_amdgcn_sched_barrier(0); }
#define VMW0  { asm volatile("s_waitcnt vmcnt(0)" ::: "memory"); \
                __builtin_amdgcn_sched_barrier(0); }

    // prologue: tile0 fully into buf0 (8 loads), then A1,B1,B2 of tile1 (6).
    STAGE_A(0, 0, 0);   STAGE_B(0, 0, 0);   STAGE_B(0, 0, 128);  STAGE_A(0, 0, 128);
    STAGE_A(1, 1, 0);   STAGE_B(1, 1, 0);   STAGE_B(1, 1, 128);
    VMW6; BAR2;

    const int nit = NT >> 1;
    for (int it = 0; it < nit - 1; ++it) {
        const int t1 = 2 * it + 1;
        // ph1: Q00(t0) buf0           | stage A2(t1) -> buf1
        LDA_G(0, 0); LDB_G(0, 0, Bf);
        STAGE_A(1, t1, 128);
        BAR1; MFMA_Q(0, 0, Bf); BAR2;
        // ph2: Q01(t0)                | stage A1(t0+2) -> buf0
        LDB_G(0, 128, Bs2);
        STAGE_A(0, t1 + 1, 0);
        BAR1; MFMA_Q(0, 2, Bs2); BAR2;
        // ph3: Q11(t0)                | stage B1(t0+2) -> buf0
        LDA_G(0, 128);
        STAGE_B(0, t1 + 1, 0);
        BAR1; MFMA_Q(4, 2, Bs2); BAR2;
        // ph4: Q10(t0)                | stage B2(t0+2) -> buf0 | vmcnt(6)
        STAGE_B(0, t1 + 1, 128);
        BAR1; MFMA_Q(4, 0, Bf); VMW6; BAR2;
        // ph5: Q00(t1) buf1           | stage A2(t0+2) -> buf0
        LDA_G(1, 0); LDB_G(1, 0, Bf);
        STAGE_A(0, t1 + 1, 128);
        BAR1; MFMA_Q(0, 0, Bf); BAR2;
        // ph6: Q01(t1)                | stage A1(t1+2) -> buf1
        LDB_G(1, 128, Bs2);
        STAGE_A(1, t1 + 2, 0);
        BAR1; MFMA_Q(0, 2, Bs2); BAR2;
        // ph7: Q11(t1)                | stage B1(t1+2) -> buf1
        LDA_G(1, 128);
        STAGE_B(1, t1 + 2, 0);
        BAR1; MFMA_Q(4, 2, Bs2); BAR2;
        // ph8: Q10(t1)                | stage B2(t1+2) -> buf1 | vmcnt(6)
        STAGE_B(1, t1 + 2, 128);
        BAR1; MFMA_Q(4, 0, Bf); VMW6; BAR2;
    }

    // peeled final iteration (t0 = NT-2 in buf0; t1 = NT-1: A1,B1,B2 in
    // flight -> buf1). Only one real stage left (A2 of t1); vmcnt(0) at ph4.
    {
        const int t1 = NT - 1;
        LDA_G(0, 0); LDB_G(0, 0, Bf);
        STAGE_A(1, t1, 128);
        BAR1; MFMA_Q(0, 0, Bf); BAR2;
        LDB_G(0, 128, Bs2);
        BAR1; MFMA_Q(0, 2, Bs2); BAR2;
        LDA_G(0, 128);
        BAR1; MFMA_Q(4, 2, Bs2); BAR2;
        BAR1; MFMA_Q(4, 0, Bf); VMW0; BAR2;
        LDA_G(1, 0); LDB_G(1, 0, Bf);
        BAR1; MFMA_Q(0, 0, Bf); BAR2;
        LDB_G(1, 128, Bs2);
        BAR1; MFMA_Q(0, 2, Bs2); BAR2;
        LDA_G(1, 128);
        BAR1; MFMA_Q(4, 2, Bs2); BAR2;
        BAR1; MFMA_Q(4, 0, Bf); BAR2;
    }

    // epilogue: C/D layout col=lane&15, row=(lane>>4)*4+reg
    const int col  = lane & 15;
    const int row4 = (lane >> 4) * 4;
#pragma unroll
    for (int j = 0; j < 4; ++j) {
        const int n = n0 + wc * 64 + j * 16 + col;
        const float bj = BIAS ? bias[n] : 0.f;
#pragma unroll
        for (int i = 0; i < 8; ++i) {
#pragma unroll
            for (int r = 0; r < 4; ++r) {
                const int m = m0 + wr * 128 + i * 16 + row4 + r;
                const float v = acc[i][j][r] + bj;
                if constexpr (sizeof(OT) == 2) C[(size_t)m * N + n] = f2b(v);
                else                            C[(size_t)m * N + n] = v;
            }
        }
    }
#undef KOF
#undef STAGE_A
#undef STAGE_B
#undef LDA_G
#undef LDB_G
#undef MFMA_Q
#undef BAR1
#undef BAR2
#undef VMW6
#undef VMW0
}

// ---------------------------------------------------------------------------
// prep_x: one pass over x producing xb (bf16, same layout) and xT (bf16,
// transposed). 64x64 tile through LDS.
// ---------------------------------------------------------------------------
__global__ __launch_bounds__(256) void prep_x(
    const float* __restrict__ in, unsigned short* __restrict__ xb,
    unsigned short* __restrict__ xT)
{
    __shared__ unsigned short tile[64][68];
    const int t  = threadIdx.x;
    const int c0 = blockIdx.x * 64;   // d
    const int r0 = blockIdx.y * 64;   // token
    const int tr = t >> 4, tc4 = (t & 15) * 4;
#pragma unroll
    for (int i = 0; i < 4; ++i) {
        const int r = tr + i * 16;
        const float4 v = *(const float4*)&in[(size_t)(r0 + r) * DDIM + c0 + tc4];
        ushort4 o;
        o.x = f2b(v.x); o.y = f2b(v.y); o.z = f2b(v.z); o.w = f2b(v.w);
        *(ushort4*)&xb[(size_t)(r0 + r) * DDIM + c0 + tc4] = o;
        tile[tc4 + 0][r] = o.x; tile[tc4 + 1][r] = o.y;
        tile[tc4 + 2][r] = o.z; tile[tc4 + 3][r] = o.w;
    }
    __syncthreads();
#pragma unroll
    for (int i = 0; i < 4; ++i) {
        const int r = tr + i * 16;
        ushort4 o;
        o.x = tile[r][tc4 + 0]; o.y = tile[r][tc4 + 1];
        o.z = tile[r][tc4 + 2]; o.w = tile[r][tc4 + 3];
        *(ushort4*)&xT[(size_t)(c0 + r) * TOKENS + r0 + tc4] = o;
    }
}

// ---------------------------------------------------------------------------
// elementwise fp32 -> bf16 cast, 8 elems/thread (phi_w only)
// ---------------------------------------------------------------------------
__global__ __launch_bounds__(256) void cast_f32_bf16(
    const float* __restrict__ in, unsigned short* __restrict__ out)
{
    const size_t i = (size_t)(blockIdx.x * 256 + threadIdx.x) * 8;
    const float4 a = *(const float4*)&in[i];
    const float4 b = *(const float4*)&in[i + 4];
    ushort4 o0, o1;
    o0.x = f2b(a.x); o0.y = f2b(a.y); o0.z = f2b(a.z); o0.w = f2b(a.w);
    o1.x = f2b(b.x); o1.y = f2b(b.y); o1.z = f2b(b.z); o1.w = f2b(b.w);
    *(ushort4*)&out[i]     = o0;
    *(ushort4*)&out[i + 4] = o1;
}

// ---------------------------------------------------------------------------
// softmax_both on BF16 logits: one pass produces DbT (transposed dispatch)
// with online (M,S) merge for combine; pass2 re-reads (warm) for Cb.
// Block = 32 tokens x all 2048 slots in 8 chunks of 256.
// ---------------------------------------------------------------------------
__global__ __launch_bounds__(256) void softmax_both(
    const unsigned short* __restrict__ logits,
    unsigned short* __restrict__ DbT, unsigned short* __restrict__ Cb)
{
    __shared__ float ls[8][32][33];      // [n_local][tok][p], pad -> low conflict
    __shared__ float Mv[32][33], Sv[32][33];
    const int tid  = threadIdx.x;
    const int tok0 = blockIdx.x * 32;
    const int tok  = tid & 31;

    {   // init combine stats
        const int tk = tid >> 3, pp = (tid & 7) * 4;
#pragma unroll
        for (int q = 0; q < 4; ++q) { Mv[tk][pp + q] = -1e30f; Sv[tk][pp + q] = 0.f; }
    }
    __syncthreads();

    for (int c = 0; c < 8; ++c) {
        // load chunk: 32 tok x 256 slots, bf16x8 per thread x 4
#pragma unroll
        for (int i = 0; i < 4; ++i) {
            const int flat = i * 256 + tid;
            const int row  = flat >> 5;          // token 0..31
            const int c8   = (flat & 31) * 8;    // slot-in-chunk 0..248
            const unsigned short* p = &logits[(size_t)(tok0 + row) * NSLOTS + c * 256 + c8];
            const ushort4 u0 = *(const ushort4*)&p[0];
            const ushort4 u1 = *(const ushort4*)&p[4];
            float* b = &ls[c8 >> 5][row][c8 & 31];
            b[0] = b2f(u0.x); b[1] = b2f(u0.y); b[2] = b2f(u0.z); b[3] = b2f(u0.w);
            b[4] = b2f(u1.x); b[5] = b2f(u1.y); b[6] = b2f(u1.z); b[7] = b2f(u1.w);
        }
        __syncthreads();

        // dispatch: thread (tok, n_local = tid>>5); serial over p
        {
            const int nl = tid >> 5;
            const float* r = ls[nl][tok];
            float m = r[0];
#pragma unroll
            for (int p = 1; p < PSLOT; ++p) m = fmaxf(m, r[p]);
            float s = 0.f;
#pragma unroll
            for (int p = 0; p < PSLOT; ++p) s += __expf(r[p] - m);
            const float inv = 1.f / s;
            unsigned short* o = &DbT[(size_t)(c * 256 + nl * 32) * TOKENS + tok0 + tok];
#pragma unroll
            for (int p = 0; p < PSLOT; ++p)
                o[(size_t)p * TOKENS] = f2b(__expf(r[p] - m) * inv);
        }

        // combine online update: thread (tok, pg = tid>>5) owns p = pg*4+k
        {
            const int pg = tid >> 5;
#pragma unroll
            for (int k = 0; k < 4; ++k) {
                const int p = pg * 4 + k;
                float m8 = ls[0][tok][p];
#pragma unroll
                for (int n = 1; n < 8; ++n) m8 = fmaxf(m8, ls[n][tok][p]);
                float s8 = 0.f;
#pragma unroll
                for (int n = 0; n < 8; ++n) s8 += __expf(ls[n][tok][p] - m8);
                const float M = Mv[tok][p], S = Sv[tok][p];
                const float Mn = fmaxf(M, m8);
                Sv[tok][p] = S * __expf(M - Mn) + s8 * __expf(m8 - Mn);
                Mv[tok][p] = Mn;
            }
        }
        __syncthreads();
    }

    {   // invert S in place
        const int tk = tid >> 3, pp = (tid & 7) * 4;
#pragma unroll
        for (int q = 0; q < 4; ++q) Sv[tk][pp + q] = 1.f / Sv[tk][pp + q];
    }
    __syncthreads();

    // pass2: Cb = exp(l - M) * (1/S), re-read bf16 logits (warm)
    for (int c = 0; c < 8; ++c) {
#pragma unroll
        for (int i = 0; i < 4; ++i) {
            const int flat = i * 256 + tid;
            const int row  = flat >> 5;
            const int c8   = (flat & 31) * 8;
            const int p    = c8 & 31;
            const unsigned short* q = &logits[(size_t)(tok0 + row) * NSLOTS + c * 256 + c8];
            const ushort4 u0 = *(const ushort4*)&q[0];
            const ushort4 u1 = *(const ushort4*)&q[4];
            ushort4 o0, o1;
            o0.x = f2b(__expf(b2f(u0.x) - Mv[row][p + 0]) * Sv[row][p + 0]);
            o0.y = f2b(__expf(b2f(u0.y) - Mv[row][p + 1]) * Sv[row][p + 1]);
            o0.z = f2b(__expf(b2f(u0.z) - Mv[row][p + 2]) * Sv[row][p + 2]);
            o0.w = f2b(__expf(b2f(u0.w) - Mv[row][p + 3]) * Sv[row][p + 3]);
            o1.x = f2b(__expf(b2f(u1.x) - Mv[row][p + 4]) * Sv[row][p + 4]);
            o1.y = f2b(__expf(b2f(u1.y) - Mv[row][p + 5]) * Sv[row][p + 5]);
            o1.z = f2b(__expf(b2f(u1.z) - Mv[row][p + 6]) * Sv[row][p + 6]);
            o1.w = f2b(__expf(b2f(u1.w) - Mv[row][p + 7]) * Sv[row][p + 7]);
            unsigned short* d = &Cb[(size_t)(tok0 + row) * NSLOTS + c * 256 + c8];
            *(ushort4*)&d[0] = o0;
            *(ushort4*)&d[4] = o1;
        }
    }
}

// ---------------------------------------------------------------------------
// split-K reduce (bf16 partials) -> clip -> LayerNorm -> tanh.
// One block per slot row.
// ---------------------------------------------------------------------------
__global__ __launch_bounds__(256) void reduce_ln_tanh(
    const unsigned short* __restrict__ parts, float* __restrict__ Xt)
{
    const int tid = threadIdx.x;
    const size_t off = (size_t)blockIdx.x * DDIM + tid * 4;
    __shared__ float red1[4], red2[4];

    float4 v = {0.f, 0.f, 0.f, 0.f};
#pragma unroll
    for (int s = 0; s < KSPLIT; ++s) {
        const ushort4 p = *(const ushort4*)&parts[(size_t)s * NSLOTS * DDIM + off];
        v.x += b2f(p.x); v.y += b2f(p.y); v.z += b2f(p.z); v.w += b2f(p.w);
    }
    v.x = fminf(fmaxf(v.x, -33000.f), 65000.f);
    v.y = fminf(fmaxf(v.y, -33000.f), 65000.f);
    v.z = fminf(fmaxf(v.z, -33000.f), 65000.f);
    v.w = fminf(fmaxf(v.w, -33000.f), 65000.f);

    float s = v.x + v.y + v.z + v.w;
#pragma unroll
    for (int off2 = 32; off2 > 0; off2 >>= 1) s += __shfl_down(s, off2);
    if ((tid & 63) == 0) red1[tid >> 6] = s;
    __syncthreads();
    const float mu = (red1[0] + red1[1] + red1[2] + red1[3]) * (1.f / DDIM);

    const float dx = v.x - mu, dy = v.y - mu, dz = v.z - mu, dw = v.w - mu;
    float q = dx * dx + dy * dy + dz * dz + dw * dw;
#pragma unroll
    for (int off2 = 32; off2 > 0; off2 >>= 1) q += __shfl_down(q, off2);
    if ((tid & 63) == 0) red2[tid >> 6] = q;
    __syncthreads();
    const float var = (red2[0] + red2[1] + red2[2] + red2[3]) * (1.f / DDIM);
    const float sc = rsqrtf(var + LN_EPS);

    float4 o;
    o.x = tanhf(dx * sc); o.y = tanhf(dy * sc);
    o.z = tanhf(dz * sc); o.w = tanhf(dw * sc);
    *(float4*)&Xt[off] = o;
}

// ---------------------------------------------------------------------------
// Per-expert GEMM v3 (fp32 FMA, HBM-bound on one-shot 256 MB read of W).
// 512 threads (8 waves/CU, was 4), h-tile 256, BK=32, double-buffered via
// global_load_lds: UNIFORM 6 loads/thread/tile (4x16B W + 2x4B Xt) so the
// per-wave vmcnt(6) exactly covers the previous tile; raw s_barrier (no
// compiler vmcnt(0) drain). 32 iters. Accumulation order (k ascending)
// bitwise-identical to v2. Fused transposed bf16 output via LDS repack.
// LDS: Bs 64KB + As 8KB + ty 18KB = 90KB -> 1 block/CU, 8 waves.
// Grid (HDIM/256, NEXP) = 256 blocks = 1/CU.
// ---------------------------------------------------------------------------
__global__ __launch_bounds__(512, 2) void expert_gemm(
    const float* __restrict__ Xt, const float* __restrict__ W,
    const float* __restrict__ bias, unsigned short* __restrict__ YtT)
{
    const int n   = blockIdx.y;
    const int h0  = blockIdx.x * 256;
    const int tid = threadIdx.x;
    __shared__ float As[2][32][32];          // [buf][slot][k]    8 KB
    __shared__ float Bs[2][32][256];         // [buf][k][h]      64 KB
    __shared__ unsigned short ty[256][36];   // repack [h][slot] 18 KB

    const int r2 = tid >> 5;          // 0..15 (slot rows r2 and r2+16)
    const int c8 = (tid & 31) * 8;    // 0..248 (h col)
    float acc0[8], acc1[8];
#pragma unroll
    for (int j = 0; j < 8; ++j) { acc0[j] = 0.f; acc1[j] = 0.f; }

    const float* Wn = W + (size_t)n * DDIM * HDIM;
    const float* Xn = Xt + (size_t)n * 32 * DDIM;

    // stage tile t (k0 = t*32): B = W[k0..+32][h0..+256] (32KB, 4x16B/thr),
    // A = Xt[0..32][k0..+32] (4KB, 2x4B/thr). All LDS dests lane-linear.
#define EG_STAGE(T, BUF) { \
    const int k0_ = (T) * 32; \
    _Pragma("unroll") for (int i = 0; i < 4; ++i) { \
        const int flat = i * 512 + tid; \
        const int brow = flat >> 6, bc4 = (flat & 63) * 4; \
        load_lds16(Wn + (size_t)(k0_ + brow) * HDIM + h0 + bc4, \
                   &Bs[BUF][brow][bc4]); } \
    _Pragma("unroll") for (int i = 0; i < 2; ++i) { \
        const int flat = i * 512 + tid; \
        const int arow = flat >> 5, ac = flat & 31; \
        load_lds4(Xn + (size_t)arow * DDIM + k0_ + ac, &As[BUF][arow][ac]); } }

    EG_STAGE(0, 0);
    for (int t = 0; t < 32; ++t) {
        const int buf = t & 1;
        if (t < 31) {
            EG_STAGE(t + 1, (t + 1) & 1);
            asm volatile("s_waitcnt vmcnt(6)" ::: "memory");
        } else {
            asm volatile("s_waitcnt vmcnt(0)" ::: "memory");
        }
        __builtin_amdgcn_sched_barrier(0);
        __builtin_amdgcn_s_barrier();           // tile t landed for all waves
#pragma unroll
        for (int kk = 0; kk < 32; ++kk) {
            const float a0 = As[buf][r2][kk];
            const float a1 = As[buf][r2 + 16][kk];
            const float4 b0 = *(const float4*)&Bs[buf][kk][c8];
            const float4 b1 = *(const float4*)&Bs[buf][kk][c8 + 4];
            acc0[0] = fmaf(a0, b0.x, acc0[0]); acc0[1] = fmaf(a0, b0.y, acc0[1]);
            acc0[2] = fmaf(a0, b0.z, acc0[2]); acc0[3] = fmaf(a0, b0.w, acc0[3]);
            acc0[4] = fmaf(a0, b1.x, acc0[4]); acc0[5] = fmaf(a0, b1.y, acc0[5]);
            acc0[6] = fmaf(a0, b1.z, acc0[6]); acc0[7] = fmaf(a0, b1.w, acc0[7]);
            acc1[0] = fmaf(a1, b0.x, acc1[0]); acc1[1] = fmaf(a1, b0.y, acc1[1]);
            acc1[2] = fmaf(a1, b0.z, acc1[2]); acc1[3] = fmaf(a1, b0.w, acc1[3]);
            acc1[4] = fmaf(a1, b1.x, acc1[4]); acc1[5] = fmaf(a1, b1.y, acc1[5]);
            acc1[6] = fmaf(a1, b1.z, acc1[6]); acc1[7] = fmaf(a1, b1.w, acc1[7]);
        }
        __builtin_amdgcn_s_barrier();           // all waves done reading buf
    }
#undef EG_STAGE

    const float* bn = bias + (size_t)n * HDIM + h0;
#pragma unroll
    for (int j = 0; j < 8; ++j) {
        const float bj = bn[c8 + j];
        ty[c8 + j][r2]      = f2b(acc0[j] + bj);
        ty[c8 + j][r2 + 16] = f2b(acc1[j] + bj);
    }
    __syncthreads();

    // write out: 256 h-rows x 32 slots; thread -> (row = tid>>1, half q)
    const int row = tid >> 1, q = (tid & 1) * 16;
    unsigned short* dst = &YtT[(size_t)(h0 + row) * NSLOTS + n * 32 + q];
#pragma unroll
    for (int u = 0; u < 4; ++u)
        *(ushort4*)&dst[u * 4] = *(const ushort4*)&ty[row][q + u * 4];
}

// ---------------------------------------------------------------------------
extern "C" void kernel_launch(void* const* d_in, const int* in_sizes, int n_in,
                              void* d_out, int out_size, void* d_ws, size_t ws_size,
                              hipStream_t stream)
{
    const float* x        = (const float*)d_in[0];  // [16384, 1024]
    const float* phi_w    = (const float*)d_in[1];  // [2048, 1024]
    const float* phi_b    = (const float*)d_in[2];  // [2048]
    const float* expert_w = (const float*)d_in[3];  // [64, 1024, 1024]
    const float* expert_b = (const float*)d_in[4];  // [64, 1024]
    float* out = (float*)d_out;                     // [16384, 1024]

    char* ws = (char*)d_ws;
    const size_t MB = 1u << 20;
    unsigned short* xb     = (unsigned short*)(ws);              // 32 MB
    unsigned short* xT     = (unsigned short*)(ws +  32 * MB);   // 32 MB
    unsigned short* pwb    = (unsigned short*)(ws +  64 * MB);   //  4 MB
    unsigned short* logbf  = (unsigned short*)(ws +  68 * MB);   // 64 MB (bf16)
    unsigned short* DbT    = (unsigned short*)(ws + 132 * MB);   // 64 MB
    unsigned short* Cb     = (unsigned short*)(ws + 196 * MB);   // 64 MB
    unsigned short* parts  = (unsigned short*)(ws + 260 * MB);   // 32 MB (bf16)
    float*          Xt     = (float*)(ws + 292 * MB);            //  8 MB
    unsigned short* YtT    = (unsigned short*)(ws + 300 * MB);   //  4 MB

    // 0. prep: x -> xb + xT (one read), phi_w -> bf16
    prep_x<<<dim3(DDIM / 64, TOKENS / 64), 256, 0, stream>>>(x, xb, xT);
    cast_f32_bf16<<<NSLOTS * DDIM / (256 * 8), 256, 0, stream>>>(phi_w, pwb);

    // 1. logits = x @ phi_w^T + phi_b   (8-phase 256^2 MFMA, bf16 out)
    gemm_nt_256<true, unsigned short>
        <<<dim3(NSLOTS / 256, TOKENS / 256), 512, 0, stream>>>(
            xb, pwb, phi_b, logbf, TOKENS, NSLOTS, DDIM);

    // 2. fused dispatch (-> DbT, transposed) + combine (-> Cb) softmax
    softmax_both<<<TOKENS / 32, 256, 0, stream>>>(logbf, DbT, Cb);

    // 3. X_tilde partials = D^T @ x, split-K 8, bf16 partial out
    gemm_nt_256<false, unsigned short>
        <<<dim3(DDIM / 256, NSLOTS / 256, KSPLIT), 512, 0, stream>>>(
            DbT, xT, nullptr, parts, NSLOTS, DDIM, TOKENS);

    // 4. reduce splits -> clip -> LN -> tanh
    reduce_ln_tanh<<<NSLOTS, 256, 0, stream>>>(parts, Xt);

    // 5. per-expert linear (fp32, 8-wave pipelined), fused transposed bf16 out
    expert_gemm<<<dim3(HDIM / 256, NEXP), 512, 0, stream>>>(
        Xt, expert_w, expert_b, YtT);

    // 6. Y = C @ Y_tilde   (8-phase 256^2 MFMA, 256 blocks)
    gemm_nt_256<false, float>
        <<<dim3(HDIM / 256, TOKENS / 256), 512, 0, stream>>>(
            Cb, YtT, nullptr, out, TOKENS, HDIM, NSLOTS);
}

// Round 7
// 729.176 us; speedup vs baseline: 1.0224x; 1.0224x over previous
//
#include <hip/hip_runtime.h>
#include <hip/hip_bf16.h>
#include <math.h>

// Problem constants
#define TOKENS   16384        // T*Z
#define DDIM     1024
#define NEXP     64
#define PSLOT    32
#define NSLOTS   2048         // NEXP*PSLOT
#define HDIM     1024
#define LN_EPS   1e-5f
#define KSPLIT   8            // split-K factor for GEMM2 (D^T x)

typedef __bf16 b16x8 __attribute__((ext_vector_type(8)));
typedef float  f32x4 __attribute__((ext_vector_type(4)));

__device__ __forceinline__ unsigned short f2b(float f) {
    union { float f; unsigned u; } v; v.f = f;
    unsigned r = v.u + 0x7FFF + ((v.u >> 16) & 1);   // RNE
    return (unsigned short)(r >> 16);
}
__device__ __forceinline__ float b2f(unsigned short u) {
    union { unsigned u; float f; } v; v.u = ((unsigned)u) << 16; return v.f;
}

__device__ __forceinline__ void load_lds16(const void* g, void* l) {
    __builtin_amdgcn_global_load_lds(
        (const __attribute__((address_space(1))) void*)g,
        (__attribute__((address_space(3))) void*)l, 16, 0, 0);
}

// ---------------------------------------------------------------------------
// 256x256 8-phase pipelined bf16 MFMA GEMM, NT layout:
//   C[M,N] = A[M,K] * B[N,K]^T (+ bias over N), split-K via gridDim.z.
// OT = float (f32 out) or unsigned short (bf16 out, halves epilogue traffic).
// 512 threads = 8 waves (2 M x 4 N), per-wave output 128x64.
// BK=64; LDS = 2 bufs x (A 256x64 + B 256x64) bf16 = 128KB.
// Counted vmcnt(6) at phases 4/8 only; final iteration peeled. XCD-aware
// block swizzle (A-panel L2 reuse). XOR k-slot LDS swizzle (conflict-free).
// ---------------------------------------------------------------------------
template<bool BIAS, typename OT>
__global__ __launch_bounds__(512, 2) void gemm_nt_256(
    const unsigned short* __restrict__ A,   // [M, K] bf16
    const unsigned short* __restrict__ B,   // [N, K] bf16
    const float* __restrict__ bias,          // [N] or null
    OT* __restrict__ C,                      // [gridDim.z][M, N]
    int M, int N, int K)
{
    __shared__ unsigned short lds[2][2][256 * 64];   // [buf][A/B][r'*64+col]
    const int tid  = threadIdx.x;
    const int wave = tid >> 6;
    const int lane = tid & 63;
    const int wr = wave >> 2;        // 0..1
    const int wc = wave & 3;         // 0..3
    const int fr = lane & 15;
    const int fs = lane >> 4;        // 0..3
    const int kswz = ((lane & 7) ^ (lane >> 3)) * 8;  // pre-swizzled global k

    // XCD-aware swizzle: contiguous chunk of output tiles per XCD (T1, m204)
    const int gx  = (int)gridDim.x, gy = (int)gridDim.y;
    const int nwg = gx * gy;
    const int wg  = (int)blockIdx.y * gx + (int)blockIdx.x;
    const int swz = (wg & 7) * (nwg >> 3) + (wg >> 3);
    const int m0 = (swz / gx) * 256;
    const int n0 = (swz % gx) * 256;

    const int kc = K / gridDim.z;
    const int kb = blockIdx.z * kc;
    C += (size_t)blockIdx.z * M * N;
    const int NT = kc >> 6;          // K-tiles (>=16 for all our shapes)

    f32x4 acc[8][4] = {};
    b16x8 Ag[4][2], Bf[2][2], Bs2[2][2];

#define KOF(T)   (kb + (T) * 64)

#define STAGE_A(BUF, T, R0) { \
    const int k0_ = KOF(T); \
    _Pragma("unroll") for (int hh = 0; hh < 2; ++hh) { \
        const int rp_ = (R0) + hh * 64 + wave * 8 + (lane >> 3); \
        const int L_  = ((rp_ >> 6) & 1) * 128 + ((rp_ >> 7) & 1) * 64 + (rp_ & 63); \
        load_lds16(A + (size_t)(m0 + L_) * K + k0_ + kswz, \
                   &lds[BUF][0][((R0) + hh * 64 + wave * 8) * 64]); } }

#define STAGE_B(BUF, T, R0) { \
    const int k0_ = KOF(T); \
    _Pragma("unroll") for (int hh = 0; hh < 2; ++hh) { \
        const int rp_ = (R0) + hh * 64 + wave * 8 + (lane >> 3); \
        const int L_  = ((rp_ >> 5) & 3) * 64 + ((rp_ >> 7) & 1) * 32 + (rp_ & 31); \
        load_lds16(B + (size_t)(n0 + L_) * K + k0_ + kswz, \
                   &lds[BUF][1][((R0) + hh * 64 + wave * 8) * 64]); } }

#define LDA_G(BUF, IBASE) \
    _Pragma("unroll") for (int ii = 0; ii < 4; ++ii) { \
        const int rp_ = (IBASE) + 64 * wr + ii * 16 + fr; \
        _Pragma("unroll") for (int h = 0; h < 2; ++h) \
            Ag[ii][h] = *(const b16x8*)&lds[BUF][0][rp_ * 64 + (((h * 4 + fs) ^ (rp_ & 7)) * 8)]; }

#define LDB_G(BUF, JBASE, DST) \
    _Pragma("unroll") for (int jj = 0; jj < 2; ++jj) { \
        const int rp_ = (JBASE) + 32 * wc + jj * 16 + fr; \
        _Pragma("unroll") for (int h = 0; h < 2; ++h) \
            DST[jj][h] = *(const b16x8*)&lds[BUF][1][rp_ * 64 + (((h * 4 + fs) ^ (rp_ & 7)) * 8)]; }

#define MFMA_Q(IB, JB, BREG) \
    __builtin_amdgcn_s_setprio(1); \
    _Pragma("unroll") for (int ii = 0; ii < 4; ++ii) \
    _Pragma("unroll") for (int jj = 0; jj < 2; ++jj) \
    _Pragma("unroll") for (int h = 0; h < 2; ++h) \
        acc[(IB) + ii][(JB) + jj] = __builtin_amdgcn_mfma_f32_16x16x32_bf16( \
            Ag[ii][h], BREG[jj][h], acc[(IB) + ii][(JB) + jj], 0, 0, 0); \
    __builtin_amdgcn_s_setprio(0);

#define BAR1  { __builtin_amdgcn_s_barrier(); __builtin_amdgcn_sched_barrier(0); }
#define BAR2  { __builtin_amdgcn_s_barrier(); }
#define VMW6  { asm volatile("s_waitcnt vmcnt(6)" ::: "memory"); \
                __builtin_amdgcn_sched_barrier(0); }
#define VMW0  { asm volatile("s_waitcnt vmcnt(0)" ::: "memory"); \
                __builtin_amdgcn_sched_barrier(0); }

    // prologue: tile0 fully into buf0 (8 loads), then A1,B1,B2 of tile1 (6).
    STAGE_A(0, 0, 0);   STAGE_B(0, 0, 0);   STAGE_B(0, 0, 128);  STAGE_A(0, 0, 128);
    STAGE_A(1, 1, 0);   STAGE_B(1, 1, 0);   STAGE_B(1, 1, 128);
    VMW6; BAR2;

    const int nit = NT >> 1;
    for (int it = 0; it < nit - 1; ++it) {
        const int t1 = 2 * it + 1;
        // ph1: Q00(t0) buf0           | stage A2(t1) -> buf1
        LDA_G(0, 0); LDB_G(0, 0, Bf);
        STAGE_A(1, t1, 128);
        BAR1; MFMA_Q(0, 0, Bf); BAR2;
        // ph2: Q01(t0)                | stage A1(t0+2) -> buf0
        LDB_G(0, 128, Bs2);
        STAGE_A(0, t1 + 1, 0);
        BAR1; MFMA_Q(0, 2, Bs2); BAR2;
        // ph3: Q11(t0)                | stage B1(t0+2) -> buf0
        LDA_G(0, 128);
        STAGE_B(0, t1 + 1, 0);
        BAR1; MFMA_Q(4, 2, Bs2); BAR2;
        // ph4: Q10(t0)                | stage B2(t0+2) -> buf0 | vmcnt(6)
        STAGE_B(0, t1 + 1, 128);
        BAR1; MFMA_Q(4, 0, Bf); VMW6; BAR2;
        // ph5: Q00(t1) buf1           | stage A2(t0+2) -> buf0
        LDA_G(1, 0); LDB_G(1, 0, Bf);
        STAGE_A(0, t1 + 1, 128);
        BAR1; MFMA_Q(0, 0, Bf); BAR2;
        // ph6: Q01(t1)                | stage A1(t1+2) -> buf1
        LDB_G(1, 128, Bs2);
        STAGE_A(1, t1 + 2, 0);
        BAR1; MFMA_Q(0, 2, Bs2); BAR2;
        // ph7: Q11(t1)                | stage B1(t1+2) -> buf1
        LDA_G(1, 128);
        STAGE_B(1, t1 + 2, 0);
        BAR1; MFMA_Q(4, 2, Bs2); BAR2;
        // ph8: Q10(t1)                | stage B2(t1+2) -> buf1 | vmcnt(6)
        STAGE_B(1, t1 + 2, 128);
        BAR1; MFMA_Q(4, 0, Bf); VMW6; BAR2;
    }

    // peeled final iteration (t0 = NT-2 in buf0; t1 = NT-1: A1,B1,B2 in
    // flight -> buf1). Only one real stage left (A2 of t1); vmcnt(0) at ph4.
    {
        const int t1 = NT - 1;
        LDA_G(0, 0); LDB_G(0, 0, Bf);
        STAGE_A(1, t1, 128);
        BAR1; MFMA_Q(0, 0, Bf); BAR2;
        LDB_G(0, 128, Bs2);
        BAR1; MFMA_Q(0, 2, Bs2); BAR2;
        LDA_G(0, 128);
        BAR1; MFMA_Q(4, 2, Bs2); BAR2;
        BAR1; MFMA_Q(4, 0, Bf); VMW0; BAR2;
        LDA_G(1, 0); LDB_G(1, 0, Bf);
        BAR1; MFMA_Q(0, 0, Bf); BAR2;
        LDB_G(1, 128, Bs2);
        BAR1; MFMA_Q(0, 2, Bs2); BAR2;
        LDA_G(1, 128);
        BAR1; MFMA_Q(4, 2, Bs2); BAR2;
        BAR1; MFMA_Q(4, 0, Bf); BAR2;
    }

    // epilogue: C/D layout col=lane&15, row=(lane>>4)*4+reg
    const int col  = lane & 15;
    const int row4 = (lane >> 4) * 4;
#pragma unroll
    for (int j = 0; j < 4; ++j) {
        const int n = n0 + wc * 64 + j * 16 + col;
        const float bj = BIAS ? bias[n] : 0.f;
#pragma unroll
        for (int i = 0; i < 8; ++i) {
#pragma unroll
            for (int r = 0; r < 4; ++r) {
                const int m = m0 + wr * 128 + i * 16 + row4 + r;
                const float v = acc[i][j][r] + bj;
                if constexpr (sizeof(OT) == 2) C[(size_t)m * N + n] = f2b(v);
                else                            C[(size_t)m * N + n] = v;
            }
        }
    }
#undef KOF
#undef STAGE_A
#undef STAGE_B
#undef LDA_G
#undef LDB_G
#undef MFMA_Q
#undef BAR1
#undef BAR2
#undef VMW6
#undef VMW0
}

// ---------------------------------------------------------------------------
// prep_x: one pass over x producing xb (bf16, same layout) and xT (bf16,
// transposed). 64x64 tile through LDS.
// ---------------------------------------------------------------------------
__global__ __launch_bounds__(256) void prep_x(
    const float* __restrict__ in, unsigned short* __restrict__ xb,
    unsigned short* __restrict__ xT)
{
    __shared__ unsigned short tile[64][68];
    const int t  = threadIdx.x;
    const int c0 = blockIdx.x * 64;   // d
    const int r0 = blockIdx.y * 64;   // token
    const int tr = t >> 4, tc4 = (t & 15) * 4;
#pragma unroll
    for (int i = 0; i < 4; ++i) {
        const int r = tr + i * 16;
        const float4 v = *(const float4*)&in[(size_t)(r0 + r) * DDIM + c0 + tc4];
        ushort4 o;
        o.x = f2b(v.x); o.y = f2b(v.y); o.z = f2b(v.z); o.w = f2b(v.w);
        *(ushort4*)&xb[(size_t)(r0 + r) * DDIM + c0 + tc4] = o;
        tile[tc4 + 0][r] = o.x; tile[tc4 + 1][r] = o.y;
        tile[tc4 + 2][r] = o.z; tile[tc4 + 3][r] = o.w;
    }
    __syncthreads();
#pragma unroll
    for (int i = 0; i < 4; ++i) {
        const int r = tr + i * 16;
        ushort4 o;
        o.x = tile[r][tc4 + 0]; o.y = tile[r][tc4 + 1];
        o.z = tile[r][tc4 + 2]; o.w = tile[r][tc4 + 3];
        *(ushort4*)&xT[(size_t)(c0 + r) * TOKENS + r0 + tc4] = o;
    }
}

// ---------------------------------------------------------------------------
// elementwise fp32 -> bf16 cast, 8 elems/thread (phi_w only)
// ---------------------------------------------------------------------------
__global__ __launch_bounds__(256) void cast_f32_bf16(
    const float* __restrict__ in, unsigned short* __restrict__ out)
{
    const size_t i = (size_t)(blockIdx.x * 256 + threadIdx.x) * 8;
    const float4 a = *(const float4*)&in[i];
    const float4 b = *(const float4*)&in[i + 4];
    ushort4 o0, o1;
    o0.x = f2b(a.x); o0.y = f2b(a.y); o0.z = f2b(a.z); o0.w = f2b(a.w);
    o1.x = f2b(b.x); o1.y = f2b(b.y); o1.z = f2b(b.z); o1.w = f2b(b.w);
    *(ushort4*)&out[i]     = o0;
    *(ushort4*)&out[i + 4] = o1;
}

// ---------------------------------------------------------------------------
// softmax_both on BF16 logits: one pass produces DbT (transposed dispatch)
// with online (M,S) merge for combine; pass2 re-reads (warm) for Cb.
// Block = 32 tokens x all 2048 slots in 8 chunks of 256.
// ---------------------------------------------------------------------------
__global__ __launch_bounds__(256) void softmax_both(
    const unsigned short* __restrict__ logits,
    unsigned short* __restrict__ DbT, unsigned short* __restrict__ Cb)
{
    __shared__ float ls[8][32][33];      // [n_local][tok][p], pad -> low conflict
    __shared__ float Mv[32][33], Sv[32][33];
    const int tid  = threadIdx.x;
    const int tok0 = blockIdx.x * 32;
    const int tok  = tid & 31;

    {   // init combine stats
        const int tk = tid >> 3, pp = (tid & 7) * 4;
#pragma unroll
        for (int q = 0; q < 4; ++q) { Mv[tk][pp + q] = -1e30f; Sv[tk][pp + q] = 0.f; }
    }
    __syncthreads();

    for (int c = 0; c < 8; ++c) {
        // load chunk: 32 tok x 256 slots, bf16x8 per thread x 4
#pragma unroll
        for (int i = 0; i < 4; ++i) {
            const int flat = i * 256 + tid;
            const int row  = flat >> 5;          // token 0..31
            const int c8   = (flat & 31) * 8;    // slot-in-chunk 0..248
            const unsigned short* p = &logits[(size_t)(tok0 + row) * NSLOTS + c * 256 + c8];
            const ushort4 u0 = *(const ushort4*)&p[0];
            const ushort4 u1 = *(const ushort4*)&p[4];
            float* b = &ls[c8 >> 5][row][c8 & 31];
            b[0] = b2f(u0.x); b[1] = b2f(u0.y); b[2] = b2f(u0.z); b[3] = b2f(u0.w);
            b[4] = b2f(u1.x); b[5] = b2f(u1.y); b[6] = b2f(u1.z); b[7] = b2f(u1.w);
        }
        __syncthreads();

        // dispatch: thread (tok, n_local = tid>>5); serial over p
        {
            const int nl = tid >> 5;
            const float* r = ls[nl][tok];
            float m = r[0];
#pragma unroll
            for (int p = 1; p < PSLOT; ++p) m = fmaxf(m, r[p]);
            float s = 0.f;
#pragma unroll
            for (int p = 0; p < PSLOT; ++p) s += __expf(r[p] - m);
            const float inv = 1.f / s;
            unsigned short* o = &DbT[(size_t)(c * 256 + nl * 32) * TOKENS + tok0 + tok];
#pragma unroll
            for (int p = 0; p < PSLOT; ++p)
                o[(size_t)p * TOKENS] = f2b(__expf(r[p] - m) * inv);
        }

        // combine online update: thread (tok, pg = tid>>5) owns p = pg*4+k
        {
            const int pg = tid >> 5;
#pragma unroll
            for (int k = 0; k < 4; ++k) {
                const int p = pg * 4 + k;
                float m8 = ls[0][tok][p];
#pragma unroll
                for (int n = 1; n < 8; ++n) m8 = fmaxf(m8, ls[n][tok][p]);
                float s8 = 0.f;
#pragma unroll
                for (int n = 0; n < 8; ++n) s8 += __expf(ls[n][tok][p] - m8);
                const float M = Mv[tok][p], S = Sv[tok][p];
                const float Mn = fmaxf(M, m8);
                Sv[tok][p] = S * __expf(M - Mn) + s8 * __expf(m8 - Mn);
                Mv[tok][p] = Mn;
            }
        }
        __syncthreads();
    }

    {   // invert S in place
        const int tk = tid >> 3, pp = (tid & 7) * 4;
#pragma unroll
        for (int q = 0; q < 4; ++q) Sv[tk][pp + q] = 1.f / Sv[tk][pp + q];
    }
    __syncthreads();

    // pass2: Cb = exp(l - M) * (1/S), re-read bf16 logits (warm)
    for (int c = 0; c < 8; ++c) {
#pragma unroll
        for (int i = 0; i < 4; ++i) {
            const int flat = i * 256 + tid;
            const int row  = flat >> 5;
            const int c8   = (flat & 31) * 8;
            const int p    = c8 & 31;
            const unsigned short* q = &logits[(size_t)(tok0 + row) * NSLOTS + c * 256 + c8];
            const ushort4 u0 = *(const ushort4*)&q[0];
            const ushort4 u1 = *(const ushort4*)&q[4];
            ushort4 o0, o1;
            o0.x = f2b(__expf(b2f(u0.x) - Mv[row][p + 0]) * Sv[row][p + 0]);
            o0.y = f2b(__expf(b2f(u0.y) - Mv[row][p + 1]) * Sv[row][p + 1]);
            o0.z = f2b(__expf(b2f(u0.z) - Mv[row][p + 2]) * Sv[row][p + 2]);
            o0.w = f2b(__expf(b2f(u0.w) - Mv[row][p + 3]) * Sv[row][p + 3]);
            o1.x = f2b(__expf(b2f(u1.x) - Mv[row][p + 4]) * Sv[row][p + 4]);
            o1.y = f2b(__expf(b2f(u1.y) - Mv[row][p + 5]) * Sv[row][p + 5]);
            o1.z = f2b(__expf(b2f(u1.z) - Mv[row][p + 6]) * Sv[row][p + 6]);
            o1.w = f2b(__expf(b2f(u1.w) - Mv[row][p + 7]) * Sv[row][p + 7]);
            unsigned short* d = &Cb[(size_t)(tok0 + row) * NSLOTS + c * 256 + c8];
            *(ushort4*)&d[0] = o0;
            *(ushort4*)&d[4] = o1;
        }
    }
}

// ---------------------------------------------------------------------------
// split-K reduce (bf16 partials) -> clip -> LayerNorm -> tanh.
// One block per slot row.
// ---------------------------------------------------------------------------
__global__ __launch_bounds__(256) void reduce_ln_tanh(
    const unsigned short* __restrict__ parts, float* __restrict__ Xt)
{
    const int tid = threadIdx.x;
    const size_t off = (size_t)blockIdx.x * DDIM + tid * 4;
    __shared__ float red1[4], red2[4];

    float4 v = {0.f, 0.f, 0.f, 0.f};
#pragma unroll
    for (int s = 0; s < KSPLIT; ++s) {
        const ushort4 p = *(const ushort4*)&parts[(size_t)s * NSLOTS * DDIM + off];
        v.x += b2f(p.x); v.y += b2f(p.y); v.z += b2f(p.z); v.w += b2f(p.w);
    }
    v.x = fminf(fmaxf(v.x, -33000.f), 65000.f);
    v.y = fminf(fmaxf(v.y, -33000.f), 65000.f);
    v.z = fminf(fmaxf(v.z, -33000.f), 65000.f);
    v.w = fminf(fmaxf(v.w, -33000.f), 65000.f);

    float s = v.x + v.y + v.z + v.w;
#pragma unroll
    for (int off2 = 32; off2 > 0; off2 >>= 1) s += __shfl_down(s, off2);
    if ((tid & 63) == 0) red1[tid >> 6] = s;
    __syncthreads();
    const float mu = (red1[0] + red1[1] + red1[2] + red1[3]) * (1.f / DDIM);

    const float dx = v.x - mu, dy = v.y - mu, dz = v.z - mu, dw = v.w - mu;
    float q = dx * dx + dy * dy + dz * dz + dw * dw;
#pragma unroll
    for (int off2 = 32; off2 > 0; off2 >>= 1) q += __shfl_down(q, off2);
    if ((tid & 63) == 0) red2[tid >> 6] = q;
    __syncthreads();
    const float var = (red2[0] + red2[1] + red2[2] + red2[3]) * (1.f / DDIM);
    const float sc = rsqrtf(var + LN_EPS);

    float4 o;
    o.x = tanhf(dx * sc); o.y = tanhf(dy * sc);
    o.z = tanhf(dz * sc); o.w = tanhf(dw * sc);
    *(float4*)&Xt[off] = o;
}

// ---------------------------------------------------------------------------
// Per-expert GEMM v2 (fp32 FMA, HBM-bound on one-shot 256 MB read of W).
// 128-wide h-tile, BK=32, double-buffered LDS via global_load_lds with
// counted vmcnt(5); RAW s_barrier (no compiler vmcnt(0) drain). 32 iters.
// 49KB LDS, 256 thr, grid 512 -> 2 blocks/CU: cross-block overlap hides
// the vmcnt waits (v3's 90KB/1-block variant lost this and regressed).
// Fused transposed bf16 output via LDS repack.
// ---------------------------------------------------------------------------
__global__ __launch_bounds__(256) void expert_gemm(
    const float* __restrict__ Xt, const float* __restrict__ W,
    const float* __restrict__ bias, unsigned short* __restrict__ YtT)
{
    const int n   = blockIdx.y;
    const int h0  = blockIdx.x * 128;
    const int tid = threadIdx.x;
    __shared__ float As[2][32][32];          // [buf][slot][k]   8 KB
    __shared__ float Bs[2][32][128];         // [buf][k][h]     32 KB
    __shared__ unsigned short ty[128][36];   // repack [h][slot] 9 KB

    const int r  = tid >> 4;          // 0..15 (slot rows r and r+16)
    const int c8 = (tid & 15) * 8;    // 0..120 (h col)
    float acc0[8], acc1[8];
#pragma unroll
    for (int j = 0; j < 8; ++j) { acc0[j] = 0.f; acc1[j] = 0.f; }

    const float* Wn = W + (size_t)n * DDIM * HDIM;
    const float* Xn = Xt + (size_t)n * 32 * DDIM;

    // stage tile t (k0 = t*32) into buf: 4 B-loads + 1 A-load per thread,
    // LDS dest lane-linear (dest = waveBase + lane*16) as gload_lds requires.
#define EG_STAGE(T, BUF) { \
    const int k0_ = (T) * 32; \
    _Pragma("unroll") for (int i = 0; i < 4; ++i) { \
        const int flat = i * 256 + tid; \
        const int brow = flat >> 5, bch = (flat & 31) * 4; \
        load_lds16(Wn + (size_t)(k0_ + brow) * HDIM + h0 + bch, \
                   &Bs[BUF][brow][bch]); } \
    { const int arow = tid >> 3, ach = (tid & 7) * 4; \
      load_lds16(Xn + (size_t)arow * DDIM + k0_ + ach, &As[BUF][arow][ach]); } }

    EG_STAGE(0, 0);
    for (int t = 0; t < 32; ++t) {
        const int buf = t & 1;
        if (t < 31) {
            EG_STAGE(t + 1, (t + 1) & 1);
            asm volatile("s_waitcnt vmcnt(5)" ::: "memory");
        } else {
            asm volatile("s_waitcnt vmcnt(0)" ::: "memory");
        }
        __builtin_amdgcn_sched_barrier(0);
        __builtin_amdgcn_s_barrier();           // tile t landed for all waves
#pragma unroll
        for (int kk = 0; kk < 32; ++kk) {
            const float a0 = As[buf][r][kk];
            const float a1 = As[buf][r + 16][kk];
            const float4 b0 = *(const float4*)&Bs[buf][kk][c8];
            const float4 b1 = *(const float4*)&Bs[buf][kk][c8 + 4];
            acc0[0] = fmaf(a0, b0.x, acc0[0]); acc0[1] = fmaf(a0, b0.y, acc0[1]);
            acc0[2] = fmaf(a0, b0.z, acc0[2]); acc0[3] = fmaf(a0, b0.w, acc0[3]);
            acc0[4] = fmaf(a0, b1.x, acc0[4]); acc0[5] = fmaf(a0, b1.y, acc0[5]);
            acc0[6] = fmaf(a0, b1.z, acc0[6]); acc0[7] = fmaf(a0, b1.w, acc0[7]);
            acc1[0] = fmaf(a1, b0.x, acc1[0]); acc1[1] = fmaf(a1, b0.y, acc1[1]);
            acc1[2] = fmaf(a1, b0.z, acc1[2]); acc1[3] = fmaf(a1, b0.w, acc1[3]);
            acc1[4] = fmaf(a1, b1.x, acc1[4]); acc1[5] = fmaf(a1, b1.y, acc1[5]);
            acc1[6] = fmaf(a1, b1.z, acc1[6]); acc1[7] = fmaf(a1, b1.w, acc1[7]);
        }
        __builtin_amdgcn_s_barrier();           // all waves done reading buf
    }
#undef EG_STAGE

    const float* bn = bias + (size_t)n * HDIM + h0;
#pragma unroll
    for (int j = 0; j < 8; ++j) {
        const float bj = bn[c8 + j];
        ty[c8 + j][r]      = f2b(acc0[j] + bj);
        ty[c8 + j][r + 16] = f2b(acc1[j] + bj);
    }
    __syncthreads();

    // write out: 128 h-rows x 32 slots; thread -> (row = tid>>1, half q)
    const int row = tid >> 1, q = (tid & 1) * 16;
    unsigned short* dst = &YtT[(size_t)(h0 + row) * NSLOTS + n * 32 + q];
#pragma unroll
    for (int u = 0; u < 4; ++u)
        *(ushort4*)&dst[u * 4] = *(const ushort4*)&ty[row][q + u * 4];
}

// ---------------------------------------------------------------------------
extern "C" void kernel_launch(void* const* d_in, const int* in_sizes, int n_in,
                              void* d_out, int out_size, void* d_ws, size_t ws_size,
                              hipStream_t stream)
{
    const float* x        = (const float*)d_in[0];  // [16384, 1024]
    const float* phi_w    = (const float*)d_in[1];  // [2048, 1024]
    const float* phi_b    = (const float*)d_in[2];  // [2048]
    const float* expert_w = (const float*)d_in[3];  // [64, 1024, 1024]
    const float* expert_b = (const float*)d_in[4];  // [64, 1024]
    float* out = (float*)d_out;                     // [16384, 1024]

    char* ws = (char*)d_ws;
    const size_t MB = 1u << 20;
    unsigned short* xb     = (unsigned short*)(ws);              // 32 MB
    unsigned short* xT     = (unsigned short*)(ws +  32 * MB);   // 32 MB
    unsigned short* pwb    = (unsigned short*)(ws +  64 * MB);   //  4 MB
    unsigned short* logbf  = (unsigned short*)(ws +  68 * MB);   // 64 MB (bf16)
    unsigned short* DbT    = (unsigned short*)(ws + 132 * MB);   // 64 MB
    unsigned short* Cb     = (unsigned short*)(ws + 196 * MB);   // 64 MB
    unsigned short* parts  = (unsigned short*)(ws + 260 * MB);   // 32 MB (bf16)
    float*          Xt     = (float*)(ws + 292 * MB);            //  8 MB
    unsigned short* YtT    = (unsigned short*)(ws + 300 * MB);   //  4 MB

    // 0. prep: x -> xb + xT (one read), phi_w -> bf16
    prep_x<<<dim3(DDIM / 64, TOKENS / 64), 256, 0, stream>>>(x, xb, xT);
    cast_f32_bf16<<<NSLOTS * DDIM / (256 * 8), 256, 0, stream>>>(phi_w, pwb);

    // 1. logits = x @ phi_w^T + phi_b   (8-phase 256^2 MFMA, bf16 out)
    gemm_nt_256<true, unsigned short>
        <<<dim3(NSLOTS / 256, TOKENS / 256), 512, 0, stream>>>(
            xb, pwb, phi_b, logbf, TOKENS, NSLOTS, DDIM);

    // 2. fused dispatch (-> DbT, transposed) + combine (-> Cb) softmax
    softmax_both<<<TOKENS / 32, 256, 0, stream>>>(logbf, DbT, Cb);

    // 3. X_tilde partials = D^T @ x, split-K 8, bf16 partial out
    gemm_nt_256<false, unsigned short>
        <<<dim3(DDIM / 256, NSLOTS / 256, KSPLIT), 512, 0, stream>>>(
            DbT, xT, nullptr, parts, NSLOTS, DDIM, TOKENS);

    // 4. reduce splits -> clip -> LN -> tanh
    reduce_ln_tanh<<<NSLOTS, 256, 0, stream>>>(parts, Xt);

    // 5. per-expert linear (fp32, 2 blocks/CU pipelined), fused bf16-T out
    expert_gemm<<<dim3(HDIM / 128, NEXP), 256, 0, stream>>>(
        Xt, expert_w, expert_b, YtT);

    // 6. Y = C @ Y_tilde   (8-phase 256^2 MFMA, 256 blocks)
    gemm_nt_256<false, float>
        <<<dim3(HDIM / 256, TOKENS / 256), 512, 0, stream>>>(
            Cb, YtT, nullptr, out, TOKENS, HDIM, NSLOTS);
}